// Round 5
// baseline (97.136 us; speedup 1.0000x reference)
//
#include <hip/hip_runtime.h>
#include <math.h>

#define NB 64
#define NL 512
#define ND 768

static constexpr float kCosEps = 1e-8f;
static constexpr double kBnEps = 1e-5;

// ---- workspace layout (bytes) ----
static constexpr size_t OFF_ACC = 0;                          // 2 doubles
static constexpr size_t OFF_CSN = 256;                        // [NB][ND] f32 colsum news (atomic)
static constexpr size_t SZ_CS   = (size_t)NB * ND * 4;        // 196608
static constexpr size_t OFF_CSP = OFF_CSN + SZ_CS;            // [NB][ND] f32 colsum post (atomic)
static constexpr size_t MEMSET_BYTES = OFF_CSP + SZ_CS;       // zero acc+csn+csp each call
static constexpr size_t OFF_COS = 393728;                     // [NB][NL] f32 cosine
static constexpr size_t SZ_BL   = (size_t)NB * NL * 4;
static constexpr size_t OFF_HI  = OFF_COS + SZ_BL;
static constexpr size_t OFF_HT  = OFF_HI + SZ_BL;
static constexpr size_t OFF_HB  = OFF_HT + SZ_BL;
static constexpr size_t OFF_ABC = OFF_HB + SZ_BL;

__device__ __forceinline__ float dot4(float4 a, float4 b) {
    return a.x * b.x + a.y * b.y + a.z * b.z + a.w * b.w;
}

// async global->LDS, 16 B per lane (wave-uniform LDS base, per-lane global src)
#define GLD16(ldst, gsrc)                                                        \
    __builtin_amdgcn_global_load_lds(                                            \
        (const __attribute__((address_space(1))) void*)(gsrc),                   \
        (__attribute__((address_space(3))) void*)(ldst), 16, 0, 0)

// counted vmcnt wait (NEVER vmcnt(0) in the hot loop - T4) + sched fence so
// the compiler cannot hoist the dependent ds_reads above the wait (rule #18).
#define WAIT_VMCNT(n)                                                            \
    do {                                                                         \
        asm volatile("s_waitcnt vmcnt(" #n ")" ::: "memory");                    \
        __builtin_amdgcn_sched_barrier(0);                                       \
    } while (0)

// ---------------------------------------------------------------------------
// k1 v5: barrier-FREE per-wave streaming pipeline.
// r4 post-mortem: __syncthreads() (= s_waitcnt vmcnt(0) + s_barrier) drained
// the just-issued prefetch every chunk -> every chunk paid the full memory
// round trip (replays with 100% L3-hit input were STILL 80 us). Each wave
// reads only the LDS it staged itself, so NO barrier is needed at all:
// per-wave double-buffered ring + counted vmcnt(6). Chunk c's loads are
// issued one full iteration ahead -> the wait is nearly free.
// grid = NB*16 (batch x 32-row tile), block = 256 = 4 waves, 8 chunks/wave,
// chunk = 1 news row + 1 post row (6 KB, 6 x GLD16). LDS 48 KB -> 3 blk/CU.
// ---------------------------------------------------------------------------
__global__ __launch_bounds__(256) void k1_cos_colsum(
    const float* __restrict__ news, const float* __restrict__ post,
    float* __restrict__ cosv, float* __restrict__ csn,
    float* __restrict__ csp)
{
    __shared__ float ring[2][4][2][ND];   // 48 KB: [slot][wave][news/post][768]
    const int b    = blockIdx.x >> 4;
    const int t16  = blockIdx.x & 15;
    const int l0   = t16 * 32;
    const int tid  = threadIdx.x;
    const int wave = tid >> 6;            // 0..3
    const int lane = tid & 63;

    // wave w owns rows l0 + w*8 + c, c = 0..7
    const float* nbase = news + ((size_t)b * NL + l0 + wave * 8) * ND + lane * 4;
    const float* pbase = post + ((size_t)b * NL + l0 + wave * 8) * ND + lane * 4;

    float nn[8], pp[8], npd[8];
    float an[12], ap[12];
#pragma unroll
    for (int k = 0; k < 12; ++k) { an[k] = 0.f; ap[k] = 0.f; }

    // ---- stage chunk 0 (this wave's row 0) ----
#pragma unroll
    for (int k = 0; k < 3; ++k) {
        GLD16(&ring[0][wave][0][k * 256], nbase + k * 256);
        GLD16(&ring[0][wave][1][k * 256], pbase + k * 256);
    }

    for (int c = 0; c < 8; ++c) {
        const int cur = c & 1;
        if (c < 7) {
            const int nxt = cur ^ 1;
            const size_t go = (size_t)(c + 1) * ND;
#pragma unroll
            for (int k = 0; k < 3; ++k) {
                GLD16(&ring[nxt][wave][0][k * 256], nbase + go + k * 256);
                GLD16(&ring[nxt][wave][1][k * 256], pbase + go + k * 256);
            }
            WAIT_VMCNT(6);   // chunk c's 6 oldest loads done; c+1 stays in flight
        } else {
            WAIT_VMCNT(0);   // last chunk: nothing else outstanding
        }

        const float4* ln = (const float4*)&ring[cur][wave][0][0];
        const float4* lp = (const float4*)&ring[cur][wave][1][0];
        const float4 A0 = ln[lane], A1 = ln[lane + 64], A2 = ln[lane + 128];
        const float4 B0 = lp[lane], B1 = lp[lane + 64], B2 = lp[lane + 128];

        nn[c]  = dot4(A0, A0) + dot4(A1, A1) + dot4(A2, A2);
        pp[c]  = dot4(B0, B0) + dot4(B1, B1) + dot4(B2, B2);
        npd[c] = dot4(A0, B0) + dot4(A1, B1) + dot4(A2, B2);

        an[0] += A0.x; an[1] += A0.y; an[2]  += A0.z; an[3]  += A0.w;
        an[4] += A1.x; an[5] += A1.y; an[6]  += A1.z; an[7]  += A1.w;
        an[8] += A2.x; an[9] += A2.y; an[10] += A2.z; an[11] += A2.w;
        ap[0] += B0.x; ap[1] += B0.y; ap[2]  += B0.z; ap[3]  += B0.w;
        ap[4] += B1.x; ap[5] += B1.y; ap[6]  += B1.z; ap[7]  += B1.w;
        ap[8] += B2.x; ap[9] += B2.y; ap[10] += B2.z; ap[11] += B2.w;
    }

    // ---- batched cross-lane reduce: 24 independent chains, 6 stages ----
#pragma unroll
    for (int m = 1; m <= 32; m <<= 1) {
#pragma unroll
        for (int c = 0; c < 8; ++c) {
            nn[c]  += __shfl_xor(nn[c], m);
            pp[c]  += __shfl_xor(pp[c], m);
            npd[c] += __shfl_xor(npd[c], m);
        }
    }
    if (lane == 0) {
#pragma unroll
        for (int c = 0; c < 8; ++c) {
            const float dn = fmaxf(sqrtf(nn[c]), kCosEps) * fmaxf(sqrtf(pp[c]), kCosEps);
            cosv[b * NL + l0 + wave * 8 + c] = npd[c] / dn;
        }
    }

    // ---- colsum block-reduce (reuse ring as flat [8][ND]) + atomics ----
    __syncthreads();   // loop traffic fully drained above; safe to repurpose
    float* fb = &ring[0][0][0][0];
    {
        float4* wn = (float4*)&fb[wave * ND];
        float4* wp = (float4*)&fb[(4 + wave) * ND];
        wn[lane]       = make_float4(an[0], an[1], an[2], an[3]);
        wn[lane + 64]  = make_float4(an[4], an[5], an[6], an[7]);
        wn[lane + 128] = make_float4(an[8], an[9], an[10], an[11]);
        wp[lane]       = make_float4(ap[0], ap[1], ap[2], ap[3]);
        wp[lane + 64]  = make_float4(ap[4], ap[5], ap[6], ap[7]);
        wp[lane + 128] = make_float4(ap[8], ap[9], ap[10], ap[11]);
    }
    __syncthreads();
    for (int i = tid; i < ND; i += 256) {
        float sn = 0.f, sp = 0.f;
#pragma unroll
        for (int w = 0; w < 4; ++w) {
            sn += fb[w * ND + i];
            sp += fb[(4 + w) * ND + i];
        }
        atomicAdd(&csn[b * ND + i], sn);
        atomicAdd(&csp[b * ND + i], sp);
    }
}

// ---------------------------------------------------------------------------
// k2: 3-tap horizontal conv of cos row (3 vertical-weight variants) +
// fp64 global sum / sum-of-squares with multiplicities (1, L-2, 1).
// ---------------------------------------------------------------------------
__global__ __launch_bounds__(256) void k2_conv_stats(
    const float* __restrict__ cosv, const float* __restrict__ g,
    float* __restrict__ hi, float* __restrict__ ht, float* __restrict__ hb,
    double* __restrict__ acc)
{
    __shared__ float row[NL + 2];
    __shared__ double sred[8];
    const int b   = blockIdx.x;
    const int tid = threadIdx.x;
    if (tid == 0) { row[0] = 0.f; row[NL + 1] = 0.f; }
    for (int j = tid; j < NL; j += 256) row[j + 1] = cosv[b * NL + j];
    __syncthreads();

    const float ci0 = g[0] + g[3] + g[6], ci1 = g[1] + g[4] + g[7], ci2 = g[2] + g[5] + g[8];
    const float ct0 = g[3] + g[6],        ct1 = g[4] + g[7],        ct2 = g[5] + g[8];
    const float cb0 = g[0] + g[3],        cb1 = g[1] + g[4],        cb2 = g[2] + g[5];

    double s = 0.0, s2 = 0.0;
    for (int j = tid; j < NL; j += 256) {
        const float a = row[j], c = row[j + 1], d = row[j + 2];
        const float vi = ci0 * a + ci1 * c + ci2 * d;
        const float vt = ct0 * a + ct1 * c + ct2 * d;
        const float vb = cb0 * a + cb1 * c + cb2 * d;
        hi[b * NL + j] = vi; ht[b * NL + j] = vt; hb[b * NL + j] = vb;
        s  += (double)vi * (NL - 2) + (double)vt + (double)vb;
        s2 += (double)vi * vi * (NL - 2) + (double)vt * vt + (double)vb * vb;
    }
    const int lane = tid & 63, wave = tid >> 6;
#pragma unroll
    for (int m = 32; m >= 1; m >>= 1) { s += __shfl_xor(s, m); s2 += __shfl_xor(s2, m); }
    if (lane == 0) { sred[wave] = s; sred[4 + wave] = s2; }
    __syncthreads();
    if (tid == 0) {
        atomicAdd(&acc[0], sred[0] + sred[1] + sred[2] + sred[3]);
        atomicAdd(&acc[1], sred[4] + sred[5] + sred[6] + sred[7]);
    }
}

// ---------------------------------------------------------------------------
// k3: normalize (global BN), z = h_hat @ W^T + b for the 3 variants,
// collapsed softmax over l (multiplicities 1, L-2, 1), sum over n.
// ---------------------------------------------------------------------------
__global__ __launch_bounds__(256) void k3_linear_softmax(
    const float* __restrict__ hi, const float* __restrict__ ht,
    const float* __restrict__ hb, const float* __restrict__ W,
    const float* __restrict__ bias, const float* __restrict__ gamma,
    const float* __restrict__ beta, const double* __restrict__ acc,
    float* __restrict__ abc)
{
    __shared__ float shi[NL], sht[NL], shb[NL];
    __shared__ float sred[12];
    const int b   = blockIdx.x;
    const int tid = threadIdx.x;

    const double N   = (double)NB * NL * NL;
    const double mu  = acc[0] / N;
    const double var = acc[1] / N - mu * mu;
    const float  sc  = gamma[0] * (float)(1.0 / sqrt(var + kBnEps));
    const float  sh  = beta[0] - (float)mu * sc;

    for (int j = tid; j < NL; j += 256) {
        shi[j] = hi[b * NL + j] * sc + sh;
        sht[j] = ht[b * NL + j] * sc + sh;
        shb[j] = hb[b * NL + j] * sc + sh;
    }
    __syncthreads();

    const float4* s4i = (const float4*)shi;
    const float4* s4t = (const float4*)sht;
    const float4* s4b = (const float4*)shb;

    float sa = 0.f, st = 0.f, sb = 0.f;
    for (int n = tid; n < NL; n += 256) {
        const float4* wr = (const float4*)(W + (size_t)n * NL);
        float zi = 0.f, zt = 0.f, zb = 0.f;
        for (int m = 0; m < NL / 4; ++m) {
            const float4 w  = wr[m];
            const float4 vi = s4i[m], vt = s4t[m], vb = s4b[m];
            zi += w.x * vi.x + w.y * vi.y + w.z * vi.z + w.w * vi.w;
            zt += w.x * vt.x + w.y * vt.y + w.z * vt.z + w.w * vt.w;
            zb += w.x * vb.x + w.y * vb.y + w.z * vb.z + w.w * vb.w;
        }
        const float bv = bias[n];
        zi += bv; zt += bv; zb += bv;
        const float M  = fmaxf(zi, fmaxf(zt, zb));
        const float ei = expf(zi - M), et = expf(zt - M), eb = expf(zb - M);
        const float r  = 1.f / ((float)(NL - 2) * ei + et + eb);
        sa += ei * r; st += et * r; sb += eb * r;
    }
    const int lane = tid & 63, wave = tid >> 6;
#pragma unroll
    for (int m = 32; m >= 1; m >>= 1) {
        sa += __shfl_xor(sa, m); st += __shfl_xor(st, m); sb += __shfl_xor(sb, m);
    }
    if (lane == 0) { sred[wave * 3] = sa; sred[wave * 3 + 1] = st; sred[wave * 3 + 2] = sb; }
    __syncthreads();
    if (tid == 0) {
        abc[b * 3 + 0] = sred[0] + sred[3] + sred[6] + sred[9];
        abc[b * 3 + 1] = sred[1] + sred[4] + sred[7] + sred[10];
        abc[b * 3 + 2] = sred[2] + sred[5] + sred[8] + sred[11];
    }
}

// ---------------------------------------------------------------------------
// k4: outputs. word_feat[b,d] = (a*colsum_n + (ct-a)*n0 + (cb-a)*nL)/L, same
// for post. grid = NB*ND/256 = 192.
// ---------------------------------------------------------------------------
__global__ __launch_bounds__(256) void k4_out(
    const float* __restrict__ news, const float* __restrict__ post,
    const float* __restrict__ csn, const float* __restrict__ csp,
    const float* __restrict__ abc, float* __restrict__ out)
{
    const int idx = blockIdx.x * 256 + threadIdx.x;
    if (idx >= NB * ND) return;
    const int b = idx / ND, d = idx - b * ND;
    const float a  = abc[b * 3 + 0];
    const float ct = abc[b * 3 + 1];
    const float cb = abc[b * 3 + 2];
    const float cn = csn[idx];
    const float cp = csp[idx];
    const size_t base = (size_t)b * NL * ND;
    const float n0 = news[base + d], nL = news[base + (size_t)(NL - 1) * ND + d];
    const float p0 = post[base + d], pL = post[base + (size_t)(NL - 1) * ND + d];
    const float invL = 1.f / NL;
    out[idx]           = (a * cn + (ct - a) * n0 + (cb - a) * nL) * invL;
    out[NB * ND + idx] = (a * cp + (ct - a) * p0 + (cb - a) * pL) * invL;
}

extern "C" void kernel_launch(void* const* d_in, const int* in_sizes, int n_in,
                              void* d_out, int out_size, void* d_ws, size_t ws_size,
                              hipStream_t stream) {
    const float* news     = (const float*)d_in[0];
    const float* post     = (const float*)d_in[1];
    const float* g        = (const float*)d_in[2];
    const float* bn_gamma = (const float*)d_in[3];
    const float* bn_beta  = (const float*)d_in[4];
    const float* lin_w    = (const float*)d_in[5];
    const float* lin_b    = (const float*)d_in[6];
    float* out = (float*)d_out;
    char*  ws  = (char*)d_ws;

    double* acc = (double*)(ws + OFF_ACC);
    float* csn  = (float*)(ws + OFF_CSN);
    float* csp  = (float*)(ws + OFF_CSP);
    float* cosv = (float*)(ws + OFF_COS);
    float* hi   = (float*)(ws + OFF_HI);
    float* ht   = (float*)(ws + OFF_HT);
    float* hb   = (float*)(ws + OFF_HB);
    float* abc  = (float*)(ws + OFF_ABC);

    // zero acc + csn + csp (atomic accumulation targets) every call
    hipMemsetAsync(ws, 0, MEMSET_BYTES, stream);

    k1_cos_colsum<<<NB * 16, 256, 0, stream>>>(news, post, cosv, csn, csp);
    k2_conv_stats<<<NB, 256, 0, stream>>>(cosv, g, hi, ht, hb, acc);
    k3_linear_softmax<<<NB, 256, 0, stream>>>(hi, ht, hb, lin_w, lin_b,
                                              bn_gamma, bn_beta, acc, abc);
    k4_out<<<192, 256, 0, stream>>>(news, post, csn, csp, abc, out);
}

// Round 6
// 87.812 us; speedup vs baseline: 1.1062x; 1.1062x over previous
//
#include <hip/hip_runtime.h>
#include <math.h>

#define NB 64
#define NL 512
#define ND 768

static constexpr float kCosEps = 1e-8f;
static constexpr double kBnEps = 1e-5;

// ---- workspace layout (bytes) ----
static constexpr size_t OFF_ACC = 0;                          // 2 doubles
static constexpr size_t OFF_CSN = 256;                        // [NB][ND] f32 colsum news (atomic)
static constexpr size_t SZ_CS   = (size_t)NB * ND * 4;        // 196608
static constexpr size_t OFF_CSP = OFF_CSN + SZ_CS;            // [NB][ND] f32 colsum post (atomic)
static constexpr size_t MEMSET_BYTES = OFF_CSP + SZ_CS;       // zero acc+csn+csp each call
static constexpr size_t OFF_COS = 393728;                     // [NB][NL] f32 cosine
static constexpr size_t SZ_BL   = (size_t)NB * NL * 4;
static constexpr size_t OFF_HI  = OFF_COS + SZ_BL;
static constexpr size_t OFF_HT  = OFF_HI + SZ_BL;
static constexpr size_t OFF_HB  = OFF_HT + SZ_BL;
static constexpr size_t OFF_ABC = OFF_HB + SZ_BL;

__device__ __forceinline__ float dot4(float4 a, float4 b) {
    return a.x * b.x + a.y * b.y + a.z * b.z + a.w * b.w;
}

// ---------------------------------------------------------------------------
// k1 v6: max bytes-in-flight, register-burst streaming (m13-style).
// Post-mortem r1-r5: FIVE structures all pinned at 201 MB / ~80 us = 2.5 TB/s,
// cold (HBM) and warm (L3, FETCH~0) identical -> not a BW ceiling; Little's
// law says in-flight bytes/CU (~30 KB) x contended latency was the cap.
// Here: wave owns 4 rows; ALL 24 float4 loads (24 KB/wave) issue as one
// burst into registers before any use; no LDS staging, no barriers, no
// shuffles until the end. grid = NB*32 = 2048 blocks x 4 waves, ~160 VGPR ->
// ~12 waves/CU -> ~288 KB in flight per CU (~10x r5).
// ---------------------------------------------------------------------------
__global__ __launch_bounds__(256) void k1_cos_colsum(
    const float* __restrict__ news, const float* __restrict__ post,
    float* __restrict__ cosv, float* __restrict__ csn,
    float* __restrict__ csp)
{
    __shared__ float red[8][ND];        // 24 KB reduce buffer
    const int b    = blockIdx.x >> 5;
    const int t    = blockIdx.x & 31;   // 16-row tile
    const int l0   = t * 16;
    const int tid  = threadIdx.x;
    const int wave = tid >> 6;          // 0..3
    const int lane = tid & 63;

    // wave owns rows l0 + wave*4 + {0..3}; row stride = 192 float4
    const size_t rbase = ((size_t)b * NL + l0 + wave * 4) * ND;
    const float4* nr = (const float4*)(news + rbase) + lane;
    const float4* pr = (const float4*)(post + rbase) + lane;

    // ---- burst-load 24 float4 (24 KB/wave in flight) ----
    float4 N[4][3], P[4][3];
#pragma unroll
    for (int r = 0; r < 4; ++r)
#pragma unroll
        for (int k = 0; k < 3; ++k)
            N[r][k] = nr[r * 192 + k * 64];
#pragma unroll
    for (int r = 0; r < 4; ++r)
#pragma unroll
        for (int k = 0; k < 3; ++k)
            P[r][k] = pr[r * 192 + k * 64];

    // ---- per-row partials + colsum accumulators ----
    float nn[4], pp[4], npd[4];
    float an[12], ap[12];
#pragma unroll
    for (int k = 0; k < 12; ++k) { an[k] = 0.f; ap[k] = 0.f; }
#pragma unroll
    for (int r = 0; r < 4; ++r) {
        nn[r]  = dot4(N[r][0], N[r][0]) + dot4(N[r][1], N[r][1]) + dot4(N[r][2], N[r][2]);
        pp[r]  = dot4(P[r][0], P[r][0]) + dot4(P[r][1], P[r][1]) + dot4(P[r][2], P[r][2]);
        npd[r] = dot4(N[r][0], P[r][0]) + dot4(N[r][1], P[r][1]) + dot4(N[r][2], P[r][2]);
#pragma unroll
        for (int k = 0; k < 3; ++k) {
            an[4 * k + 0] += N[r][k].x; an[4 * k + 1] += N[r][k].y;
            an[4 * k + 2] += N[r][k].z; an[4 * k + 3] += N[r][k].w;
            ap[4 * k + 0] += P[r][k].x; ap[4 * k + 1] += P[r][k].y;
            ap[4 * k + 2] += P[r][k].z; ap[4 * k + 3] += P[r][k].w;
        }
    }

    // ---- 12 independent shuffle-reduce chains, 6 stages ----
#pragma unroll
    for (int m = 1; m <= 32; m <<= 1) {
#pragma unroll
        for (int r = 0; r < 4; ++r) {
            nn[r]  += __shfl_xor(nn[r], m);
            pp[r]  += __shfl_xor(pp[r], m);
            npd[r] += __shfl_xor(npd[r], m);
        }
    }
    if (lane == 0) {
#pragma unroll
        for (int r = 0; r < 4; ++r) {
            const float dn = fmaxf(sqrtf(nn[r]), kCosEps) * fmaxf(sqrtf(pp[r]), kCosEps);
            cosv[b * NL + l0 + wave * 4 + r] = npd[r] / dn;
        }
    }

    // ---- colsum block-reduce + atomic accumulate ----
    {
        float4* wn = (float4*)&red[wave][0];
        float4* wp = (float4*)&red[4 + wave][0];
        wn[lane]       = make_float4(an[0], an[1], an[2], an[3]);
        wn[lane + 64]  = make_float4(an[4], an[5], an[6], an[7]);
        wn[lane + 128] = make_float4(an[8], an[9], an[10], an[11]);
        wp[lane]       = make_float4(ap[0], ap[1], ap[2], ap[3]);
        wp[lane + 64]  = make_float4(ap[4], ap[5], ap[6], ap[7]);
        wp[lane + 128] = make_float4(ap[8], ap[9], ap[10], ap[11]);
    }
    __syncthreads();
    for (int i = tid; i < ND; i += 256) {
        float sn = red[0][i] + red[1][i] + red[2][i] + red[3][i];
        float sp = red[4][i] + red[5][i] + red[6][i] + red[7][i];
        atomicAdd(&csn[b * ND + i], sn);
        atomicAdd(&csp[b * ND + i], sp);
    }
}

// ---------------------------------------------------------------------------
// k2: 3-tap horizontal conv of cos row (3 vertical-weight variants) +
// fp64 global sum / sum-of-squares with multiplicities (1, L-2, 1).
// ---------------------------------------------------------------------------
__global__ __launch_bounds__(256) void k2_conv_stats(
    const float* __restrict__ cosv, const float* __restrict__ g,
    float* __restrict__ hi, float* __restrict__ ht, float* __restrict__ hb,
    double* __restrict__ acc)
{
    __shared__ float row[NL + 2];
    __shared__ double sred[8];
    const int b   = blockIdx.x;
    const int tid = threadIdx.x;
    if (tid == 0) { row[0] = 0.f; row[NL + 1] = 0.f; }
    for (int j = tid; j < NL; j += 256) row[j + 1] = cosv[b * NL + j];
    __syncthreads();

    const float ci0 = g[0] + g[3] + g[6], ci1 = g[1] + g[4] + g[7], ci2 = g[2] + g[5] + g[8];
    const float ct0 = g[3] + g[6],        ct1 = g[4] + g[7],        ct2 = g[5] + g[8];
    const float cb0 = g[0] + g[3],        cb1 = g[1] + g[4],        cb2 = g[2] + g[5];

    double s = 0.0, s2 = 0.0;
    for (int j = tid; j < NL; j += 256) {
        const float a = row[j], c = row[j + 1], d = row[j + 2];
        const float vi = ci0 * a + ci1 * c + ci2 * d;
        const float vt = ct0 * a + ct1 * c + ct2 * d;
        const float vb = cb0 * a + cb1 * c + cb2 * d;
        hi[b * NL + j] = vi; ht[b * NL + j] = vt; hb[b * NL + j] = vb;
        s  += (double)vi * (NL - 2) + (double)vt + (double)vb;
        s2 += (double)vi * vi * (NL - 2) + (double)vt * vt + (double)vb * vb;
    }
    const int lane = tid & 63, wave = tid >> 6;
#pragma unroll
    for (int m = 32; m >= 1; m >>= 1) { s += __shfl_xor(s, m); s2 += __shfl_xor(s2, m); }
    if (lane == 0) { sred[wave] = s; sred[4 + wave] = s2; }
    __syncthreads();
    if (tid == 0) {
        atomicAdd(&acc[0], sred[0] + sred[1] + sred[2] + sred[3]);
        atomicAdd(&acc[1], sred[4] + sred[5] + sred[6] + sred[7]);
    }
}

// ---------------------------------------------------------------------------
// k3: normalize (global BN), z = h_hat @ W^T + b for the 3 variants,
// collapsed softmax over l (multiplicities 1, L-2, 1), sum over n.
// ---------------------------------------------------------------------------
__global__ __launch_bounds__(256) void k3_linear_softmax(
    const float* __restrict__ hi, const float* __restrict__ ht,
    const float* __restrict__ hb, const float* __restrict__ W,
    const float* __restrict__ bias, const float* __restrict__ gamma,
    const float* __restrict__ beta, const double* __restrict__ acc,
    float* __restrict__ abc)
{
    __shared__ float shi[NL], sht[NL], shb[NL];
    __shared__ float sred[12];
    const int b   = blockIdx.x;
    const int tid = threadIdx.x;

    const double N   = (double)NB * NL * NL;
    const double mu  = acc[0] / N;
    const double var = acc[1] / N - mu * mu;
    const float  sc  = gamma[0] * (float)(1.0 / sqrt(var + kBnEps));
    const float  sh  = beta[0] - (float)mu * sc;

    for (int j = tid; j < NL; j += 256) {
        shi[j] = hi[b * NL + j] * sc + sh;
        sht[j] = ht[b * NL + j] * sc + sh;
        shb[j] = hb[b * NL + j] * sc + sh;
    }
    __syncthreads();

    const float4* s4i = (const float4*)shi;
    const float4* s4t = (const float4*)sht;
    const float4* s4b = (const float4*)shb;

    float sa = 0.f, st = 0.f, sb = 0.f;
    for (int n = tid; n < NL; n += 256) {
        const float4* wr = (const float4*)(W + (size_t)n * NL);
        float zi = 0.f, zt = 0.f, zb = 0.f;
        for (int m = 0; m < NL / 4; ++m) {
            const float4 w  = wr[m];
            const float4 vi = s4i[m], vt = s4t[m], vb = s4b[m];
            zi += w.x * vi.x + w.y * vi.y + w.z * vi.z + w.w * vi.w;
            zt += w.x * vt.x + w.y * vt.y + w.z * vt.z + w.w * vt.w;
            zb += w.x * vb.x + w.y * vb.y + w.z * vb.z + w.w * vb.w;
        }
        const float bv = bias[n];
        zi += bv; zt += bv; zb += bv;
        const float M  = fmaxf(zi, fmaxf(zt, zb));
        const float ei = expf(zi - M), et = expf(zt - M), eb = expf(zb - M);
        const float r  = 1.f / ((float)(NL - 2) * ei + et + eb);
        sa += ei * r; st += et * r; sb += eb * r;
    }
    const int lane = tid & 63, wave = tid >> 6;
#pragma unroll
    for (int m = 32; m >= 1; m >>= 1) {
        sa += __shfl_xor(sa, m); st += __shfl_xor(st, m); sb += __shfl_xor(sb, m);
    }
    if (lane == 0) { sred[wave * 3] = sa; sred[wave * 3 + 1] = st; sred[wave * 3 + 2] = sb; }
    __syncthreads();
    if (tid == 0) {
        abc[b * 3 + 0] = sred[0] + sred[3] + sred[6] + sred[9];
        abc[b * 3 + 1] = sred[1] + sred[4] + sred[7] + sred[10];
        abc[b * 3 + 2] = sred[2] + sred[5] + sred[8] + sred[11];
    }
}

// ---------------------------------------------------------------------------
// k4: outputs. word_feat[b,d] = (a*colsum_n + (ct-a)*n0 + (cb-a)*nL)/L, same
// for post. grid = NB*ND/256 = 192.
// ---------------------------------------------------------------------------
__global__ __launch_bounds__(256) void k4_out(
    const float* __restrict__ news, const float* __restrict__ post,
    const float* __restrict__ csn, const float* __restrict__ csp,
    const float* __restrict__ abc, float* __restrict__ out)
{
    const int idx = blockIdx.x * 256 + threadIdx.x;
    if (idx >= NB * ND) return;
    const int b = idx / ND, d = idx - b * ND;
    const float a  = abc[b * 3 + 0];
    const float ct = abc[b * 3 + 1];
    const float cb = abc[b * 3 + 2];
    const float cn = csn[idx];
    const float cp = csp[idx];
    const size_t base = (size_t)b * NL * ND;
    const float n0 = news[base + d], nL = news[base + (size_t)(NL - 1) * ND + d];
    const float p0 = post[base + d], pL = post[base + (size_t)(NL - 1) * ND + d];
    const float invL = 1.f / NL;
    out[idx]           = (a * cn + (ct - a) * n0 + (cb - a) * nL) * invL;
    out[NB * ND + idx] = (a * cp + (ct - a) * p0 + (cb - a) * pL) * invL;
}

extern "C" void kernel_launch(void* const* d_in, const int* in_sizes, int n_in,
                              void* d_out, int out_size, void* d_ws, size_t ws_size,
                              hipStream_t stream) {
    const float* news     = (const float*)d_in[0];
    const float* post     = (const float*)d_in[1];
    const float* g        = (const float*)d_in[2];
    const float* bn_gamma = (const float*)d_in[3];
    const float* bn_beta  = (const float*)d_in[4];
    const float* lin_w    = (const float*)d_in[5];
    const float* lin_b    = (const float*)d_in[6];
    float* out = (float*)d_out;
    char*  ws  = (char*)d_ws;

    double* acc = (double*)(ws + OFF_ACC);
    float* csn  = (float*)(ws + OFF_CSN);
    float* csp  = (float*)(ws + OFF_CSP);
    float* cosv = (float*)(ws + OFF_COS);
    float* hi   = (float*)(ws + OFF_HI);
    float* ht   = (float*)(ws + OFF_HT);
    float* hb   = (float*)(ws + OFF_HB);
    float* abc  = (float*)(ws + OFF_ABC);

    // zero acc + csn + csp (atomic accumulation targets) every call
    hipMemsetAsync(ws, 0, MEMSET_BYTES, stream);

    k1_cos_colsum<<<NB * 32, 256, 0, stream>>>(news, post, cosv, csn, csp);
    k2_conv_stats<<<NB, 256, 0, stream>>>(cosv, g, hi, ht, hb, acc);
    k3_linear_softmax<<<NB, 256, 0, stream>>>(hi, ht, hb, lin_w, lin_b,
                                              bn_gamma, bn_beta, acc, abc);
    k4_out<<<192, 256, 0, stream>>>(news, post, csn, csp, abc, out);
}